// Round 1
// baseline (5086.700 us; speedup 1.0000x reference)
//
#include <hip/hip_runtime.h>
#include <hip/hip_bf16.h>
#include <cmath>

typedef unsigned short u16;
typedef __bf16 bf16_t;
typedef __bf16 bf16x8 __attribute__((ext_vector_type(8)));
typedef float f32x4 __attribute__((ext_vector_type(4)));

#define HDIM   768
#define NHEAD  12
#define HD     64
#define SEQ    1024
#define BATCH  2
#define NLAYER 12
#define FFI    3072
#define VOCAB  50257
#define NTOK   (BATCH*SEQ)

__device__ inline u16 f2bf(float f) {
  bf16_t h = (bf16_t)f;                 // RNE fptrunc
  return __builtin_bit_cast(u16, h);
}

// ---------------- batched NT GEMM: C[m,n] = sum_k A[m,k] * W[n,k] ----------------
// A bf16 (u16), W float or bf16 (converted during LDS staging), C float or bf16.
// Per-z base offsets: base = (z/zdiv)*strideOut + (z%zdiv)*strideIn  (elements).
#define TM 128
#define TN 128
#define BKK 64
#define LDSP 72   // padded LDS row stride (bf16 elems): breaks bank-conflict stride

template<typename WT, typename OT>
__global__ __launch_bounds__(256, 2) void gemm_nt(
    const u16* __restrict__ A, const WT* __restrict__ W, OT* __restrict__ C,
    int M, int N, int K, int lda, int ldb, int ldc,
    long long aOut, long long aIn, long long bOut, long long bIn,
    long long cOut, long long cIn, int zdiv, int causal)
{
  __shared__ __align__(16) u16 sA[TM * LDSP];
  __shared__ __align__(16) u16 sB[TN * LDSP];

  int z = blockIdx.z;
  if (zdiv > 1) {
    int zo = z / zdiv, zi = z - zo * zdiv;
    A += zo * aOut + zi * aIn;
    W += zo * bOut + zi * bIn;
    C += zo * cOut + zi * cIn;
  }
  int mt = blockIdx.x * TM;
  int nt = blockIdx.y * TN;
  if (causal && nt > mt + (TM - 1)) return;  // tile entirely above diagonal

  int t = threadIdx.x;
  int w = t >> 6, l = t & 63;
  int wm = (w >> 1) * 64, wn = (w & 1) * 64;
  int quad = l >> 4, mr = l & 15;

  f32x4 acc[4][4] = {};

  int arow = t >> 3;            // staging: thread handles rows arow+{0,32,64,96}
  int akc  = (t & 7) * 8;       // 8-elem k chunk

  for (int kt = 0; kt < K; kt += BKK) {
    #pragma unroll
    for (int i = 0; i < 4; i++) {
      int row = arow + i * 32;
      const uint4* src = (const uint4*)(A + (size_t)(mt + row) * lda + kt + akc);
      *(uint4*)(&sA[row * LDSP + akc]) = *src;
    }
    #pragma unroll
    for (int i = 0; i < 4; i++) {
      int row = arow + i * 32;
      int gr = nt + row; if (gr >= N) gr = N - 1;   // clamp (values unused if OOB)
      const WT* src = W + (size_t)gr * ldb + kt + akc;
      if constexpr (sizeof(WT) == 2) {
        *(uint4*)(&sB[row * LDSP + akc]) = *(const uint4*)src;
      } else {
        float4 f0 = *(const float4*)(src);
        float4 f1 = *(const float4*)(src + 4);
        uint4 p;
        p.x = (unsigned)f2bf(f0.x) | ((unsigned)f2bf(f0.y) << 16);
        p.y = (unsigned)f2bf(f0.z) | ((unsigned)f2bf(f0.w) << 16);
        p.z = (unsigned)f2bf(f1.x) | ((unsigned)f2bf(f1.y) << 16);
        p.w = (unsigned)f2bf(f1.z) | ((unsigned)f2bf(f1.w) << 16);
        *(uint4*)(&sB[row * LDSP + akc]) = p;
      }
    }
    __syncthreads();
    #pragma unroll
    for (int kk = 0; kk < BKK; kk += 32) {
      bf16x8 af[4], bfr[4];
      #pragma unroll
      for (int i = 0; i < 4; i++)
        af[i] = *(const bf16x8*)(&sA[(wm + i * 16 + mr) * LDSP + kk + quad * 8]);
      #pragma unroll
      for (int j = 0; j < 4; j++)
        bfr[j] = *(const bf16x8*)(&sB[(wn + j * 16 + mr) * LDSP + kk + quad * 8]);
      #pragma unroll
      for (int i = 0; i < 4; i++)
        #pragma unroll
        for (int j = 0; j < 4; j++)
          acc[i][j] = __builtin_amdgcn_mfma_f32_16x16x32_bf16(af[i], bfr[j], acc[i][j], 0, 0, 0);
    }
    __syncthreads();
  }

  // C/D layout (m89-verified): col = lane&15, row = (lane>>4)*4 + reg
  #pragma unroll
  for (int i = 0; i < 4; i++)
    #pragma unroll
    for (int j = 0; j < 4; j++)
      #pragma unroll
      for (int r = 0; r < 4; r++) {
        int gm = mt + wm + i * 16 + quad * 4 + r;
        int gn = nt + wn + j * 16 + mr;
        if (gn < N) {
          float v = acc[i][j][r];
          if constexpr (sizeof(OT) == 2) C[(size_t)gm * ldc + gn] = f2bf(v);
          else                           C[(size_t)gm * ldc + gn] = v;
        }
      }
}

// ---------------- LayerNorm row kernel: fp32 in -> bf16 out ----------------
__global__ __launch_bounds__(256) void ln_bf16(
    const float* __restrict__ x, const float* __restrict__ w,
    const float* __restrict__ b, u16* __restrict__ out)
{
  __shared__ float redA[4], redB[4];
  int row = blockIdx.x;
  const float* xr = x + (size_t)row * HDIM;
  int t = threadIdx.x;
  float v0 = xr[t], v1 = xr[t + 256], v2 = xr[t + 512];
  float s  = v0 + v1 + v2;
  float s2 = v0 * v0 + v1 * v1 + v2 * v2;
  #pragma unroll
  for (int o = 32; o > 0; o >>= 1) { s += __shfl_xor(s, o); s2 += __shfl_xor(s2, o); }
  if ((t & 63) == 0) { redA[t >> 6] = s; redB[t >> 6] = s2; }
  __syncthreads();
  float S  = redA[0] + redA[1] + redA[2] + redA[3];
  float S2 = redB[0] + redB[1] + redB[2] + redB[3];
  float mean = S * (1.0f / HDIM);
  float var  = S2 * (1.0f / HDIM) - mean * mean;
  float rstd = rsqrtf(var + 1e-5f);
  u16* orow = out + (size_t)row * HDIM;
  orow[t]       = f2bf((v0 - mean) * rstd * w[t]       + b[t]);
  orow[t + 256] = f2bf((v1 - mean) * rstd * w[t + 256] + b[t + 256]);
  orow[t + 512] = f2bf((v2 - mean) * rstd * w[t + 512] + b[t + 512]);
}

// ---------------- softmax: scale + causal + pad mask, fp32 in -> bf16 P ----------------
__global__ __launch_bounds__(256) void softmax_causal(
    const float* __restrict__ scores, u16* __restrict__ P,
    const int* __restrict__ amask)
{
  __shared__ float red[4];
  int row = blockIdx.x;            // z*SEQ + qi, z = b*NHEAD+h
  int z  = row >> 10;
  int qi = row & (SEQ - 1);
  int b  = z / NHEAD;
  const float* s = scores + (size_t)row * SEQ;
  u16* p = P + (size_t)row * SEQ;
  int t = threadIdx.x;
  float vals[4];
  float mx = -3.4e38f;
  #pragma unroll
  for (int i = 0; i < 4; i++) {
    int j = t + i * 256;
    float v = -1e9f;
    if (j <= qi && amask[b * SEQ + j] != 0) v = s[j] * 0.125f;   // 1/sqrt(64)
    vals[i] = v;
    mx = fmaxf(mx, v);
  }
  #pragma unroll
  for (int o = 32; o > 0; o >>= 1) mx = fmaxf(mx, __shfl_xor(mx, o));
  if ((t & 63) == 0) red[t >> 6] = mx;
  __syncthreads();
  mx = fmaxf(fmaxf(red[0], red[1]), fmaxf(red[2], red[3]));
  float e[4]; float sum = 0.0f;
  #pragma unroll
  for (int i = 0; i < 4; i++) { e[i] = expf(vals[i] - mx); sum += e[i]; }
  #pragma unroll
  for (int o = 32; o > 0; o >>= 1) sum += __shfl_xor(sum, o);
  __syncthreads();
  if ((t & 63) == 0) red[t >> 6] = sum;
  __syncthreads();
  float inv = 1.0f / (red[0] + red[1] + red[2] + red[3]);
  #pragma unroll
  for (int i = 0; i < 4; i++) p[t + i * 256] = f2bf(e[i] * inv);
}

// ---------------- misc elementwise ----------------
__global__ void embed_k(const int* __restrict__ ids, const float* __restrict__ tok,
                        const float* __restrict__ pos, float* __restrict__ x)
{
  int tkn = blockIdx.x;
  int sidx = tkn & (SEQ - 1);
  int id = ids[tkn];
  int t = threadIdx.x;
  #pragma unroll
  for (int i = 0; i < 3; i++) {
    int j = t + i * 256;
    x[(size_t)tkn * HDIM + j] = tok[(size_t)id * HDIM + j] + pos[(size_t)sidx * HDIM + j];
  }
}

__global__ void transpose_v(const u16* __restrict__ vb, u16* __restrict__ vT)
{
  int i = blockIdx.x * 256 + threadIdx.x;        // [B,NH,HD,S] linear
  int sidx = i & (SEQ - 1);
  int d = (i >> 10) & (HD - 1);
  int zh = i >> 16;                              // b*NHEAD + h
  int h = zh % NHEAD, b = zh / NHEAD;
  vT[i] = vb[((size_t)(b * SEQ + sidx)) * HDIM + h * HD + d];
}

__global__ void resid_add(float* __restrict__ x, const float* __restrict__ c,
                          const float* __restrict__ bias)
{
  int i = blockIdx.x * 256 + threadIdx.x;        // NTOK*HDIM
  int col = i % HDIM;
  x[i] += c[i] + bias[col];
}

__global__ void gelu_bias(const float* __restrict__ c, const float* __restrict__ bias,
                          u16* __restrict__ out)
{
  int i = blockIdx.x * 256 + threadIdx.x;        // NTOK*FFI
  int col = i % FFI;
  float v = c[i] + bias[col];
  float g = 0.5f * v * (1.0f + erff(v * 0.70710678118654752f));  // exact gelu
  out[i] = f2bf(g);
}

// ---------------- driver ----------------
extern "C" void kernel_launch(void* const* d_in, const int* in_sizes, int n_in,
                              void* d_out, int out_size, void* d_ws, size_t ws_size,
                              hipStream_t stream)
{
  const int*   ids   = (const int*)d_in[0];
  const int*   amask = (const int*)d_in[1];
  const float* tok   = (const float*)d_in[2];
  const float* pos   = (const float*)d_in[3];
  const float* ln1w  = (const float*)d_in[4];
  const float* ln1b  = (const float*)d_in[5];
  const float* qw    = (const float*)d_in[6];
  const float* kw    = (const float*)d_in[7];
  const float* vw    = (const float*)d_in[8];
  const float* ow    = (const float*)d_in[9];
  const float* ob    = (const float*)d_in[10];
  const float* ln2w  = (const float*)d_in[11];
  const float* ln2b  = (const float*)d_in[12];
  const float* w1    = (const float*)d_in[13];
  const float* b1    = (const float*)d_in[14];
  const float* w2    = (const float*)d_in[15];
  const float* b2    = (const float*)d_in[16];
  const float* lnfw  = (const float*)d_in[17];
  const float* lnfb  = (const float*)d_in[18];
  const float* lmw   = (const float*)d_in[19];

  // workspace layout (bytes) — total ~66 MB
  char* ws = (char*)d_ws;
  float* x    = (float*)(ws);                   // 2048x768 f32
  u16*   h    = (u16*)  (ws + 6291456);         // 2048x768 bf16 (LN out)
  u16*   qb   = (u16*)  (ws + 9437184);
  u16*   kb   = (u16*)  (ws + 12582912);
  u16*   vb   = (u16*)  (ws + 15728640);
  u16*   vT   = (u16*)  (ws + 18874368);        // [B,NH,HD,S] bf16
  u16*   ab   = (u16*)  (ws + 22020096);        // attention output bf16
  float* tmpC = (float*)(ws + 25165824);        // 2048x768 f32
  float* tmpF = (float*)(ws + 31457280);        // 2048x3072 f32
  u16*   ffb  = (u16*)  (ws + 56623104);        // 2048x3072 bf16   end = 69206016

  // scores/P live in d_out (411 MB, fully overwritten by lm_head at the end)
  float* scores = (float*)d_out;                          // 24x1024x1024 f32 = 100663296 B
  u16*   Pm     = (u16*)((char*)d_out + 100663296);       // 24x1024x1024 bf16

  embed_k<<<NTOK, 256, 0, stream>>>(ids, tok, pos, x);

  dim3 gp(16, 6, 1);           // 2048x768 GEMM grid
  for (int l = 0; l < NLAYER; l++) {
    ln_bf16<<<NTOK, 256, 0, stream>>>(x, ln1w + l * HDIM, ln1b + l * HDIM, h);

    gemm_nt<float, u16><<<gp, 256, 0, stream>>>(h, qw + (size_t)l * HDIM * HDIM, qb,
        NTOK, HDIM, HDIM, HDIM, HDIM, HDIM, 0, 0, 0, 0, 0, 0, 1, 0);
    gemm_nt<float, u16><<<gp, 256, 0, stream>>>(h, kw + (size_t)l * HDIM * HDIM, kb,
        NTOK, HDIM, HDIM, HDIM, HDIM, HDIM, 0, 0, 0, 0, 0, 0, 1, 0);
    gemm_nt<float, u16><<<gp, 256, 0, stream>>>(h, vw + (size_t)l * HDIM * HDIM, vb,
        NTOK, HDIM, HDIM, HDIM, HDIM, HDIM, 0, 0, 0, 0, 0, 0, 1, 0);

    transpose_v<<<6144, 256, 0, stream>>>(vb, vT);

    // scores[z,i,j] = q . k   (scale applied in softmax)
    gemm_nt<u16, float><<<dim3(8, 8, BATCH * NHEAD), 256, 0, stream>>>(qb, kb, scores,
        SEQ, SEQ, HD, HDIM, HDIM, SEQ,
        (long long)SEQ * HDIM, HD, (long long)SEQ * HDIM, HD,
        (long long)NHEAD * SEQ * SEQ, (long long)SEQ * SEQ, NHEAD, 1);

    softmax_causal<<<BATCH * NHEAD * SEQ, 256, 0, stream>>>(scores, Pm, amask);

    // a[b,i,h*64+d] = sum_j P[z,i,j] * vT[z,d,j]
    gemm_nt<u16, u16><<<dim3(8, 1, BATCH * NHEAD), 256, 0, stream>>>(Pm, vT, ab,
        SEQ, HD, SEQ, SEQ, SEQ, HDIM,
        (long long)NHEAD * SEQ * SEQ, (long long)SEQ * SEQ,
        (long long)NHEAD * HD * SEQ, (long long)HD * SEQ,
        (long long)SEQ * HDIM, HD, NHEAD, 0);

    gemm_nt<float, float><<<gp, 256, 0, stream>>>(ab, ow + (size_t)l * HDIM * HDIM, tmpC,
        NTOK, HDIM, HDIM, HDIM, HDIM, HDIM, 0, 0, 0, 0, 0, 0, 1, 0);
    resid_add<<<6144, 256, 0, stream>>>(x, tmpC, ob + l * HDIM);

    ln_bf16<<<NTOK, 256, 0, stream>>>(x, ln2w + l * HDIM, ln2b + l * HDIM, h);

    gemm_nt<float, float><<<dim3(16, 24, 1), 256, 0, stream>>>(h, w1 + (size_t)l * FFI * HDIM, tmpF,
        NTOK, FFI, HDIM, HDIM, HDIM, FFI, 0, 0, 0, 0, 0, 0, 1, 0);
    gelu_bias<<<24576, 256, 0, stream>>>(tmpF, b1 + l * FFI, ffb);
    gemm_nt<float, float><<<gp, 256, 0, stream>>>(ffb, w2 + (size_t)l * HDIM * FFI, tmpC,
        NTOK, HDIM, FFI, FFI, FFI, HDIM, 0, 0, 0, 0, 0, 0, 1, 0);
    resid_add<<<6144, 256, 0, stream>>>(x, tmpC, b2 + l * HDIM);
  }

  ln_bf16<<<NTOK, 256, 0, stream>>>(x, lnfw, lnfb, h);
  gemm_nt<float, float><<<dim3(16, 393, 1), 256, 0, stream>>>(h, lmw, (float*)d_out,
      NTOK, VOCAB, HDIM, HDIM, HDIM, VOCAB, 0, 0, 0, 0, 0, 0, 1, 0);
}